// Round 5
// baseline (2441.612 us; speedup 1.0000x reference)
//
#include <hip/hip_runtime.h>
#include <cstddef>

// SimpleLSTM: B=64, D=512, T=512, H=1024, O=1 — fp16, XCD-claimed group placement,
// padded-subflag sync, LDS-staged SECTOR-COALESCED h stores.
// MEASURED LAW (r2/r3/r4): dur == (FETCH+WRITE)/~240GB/s. r4: FETCH 201MB
// (= 2 XCD-L2 fills x (32KB h + 16KB x) x 4 groups x 512 steps, exact) +
// WRITE 319MB. WRITE decomposes as 262MB h-stores (4x inflated: each 32B row
// written as 4x8B quarters by 4 different waves -> 4 sectors) + flags + part.
// THIS REVISION: stage the 16x16 f16 h-tile in LDS (768B), sync the 4 reducer
// waves via monotonic LDS counter, then each wave stores 4 full rows with
// 4 adjacent lanes x u64 in ONE instruction -> 1x32B sector per row.
// Predicted: WRITE 319->~100MB, k_lstm 2280->~1500us.
// ws layout (~46.53 MB):
//   [0, 32MB)            xT: f16 [T=512][B=64][D=512]
//   [32MB, +12.58MB)     Wf: f16 A-frags [r=64][ks=48][mt=4][lane=64][8]
//                        (reused after weight load as out-partials
//                         part[t=512][g=4][r=64][b16=16] f32 = 8MB, atomicAdd'd)
//   [46,137,344, +256KB) h double buffer: f16 [2][B=64][H=1024]
//   [46,399,488, +128KB) subflags[g=4][r=64][mt=4] u32, stride 32 u32 (128B/flag)
//                        claim counters at ctrs[x*32+16], x=0..7 (startup only)
//                        + ready counter at index 32768
#define WS_XT_OFF   0ull
#define WS_WF_OFF   33554432ull
#define WS_HB_OFF   46137344ull
#define WS_CTR_OFF  46399488ull

typedef _Float16 f16x8 __attribute__((ext_vector_type(8)));
typedef float    f32x4 __attribute__((ext_vector_type(4)));
typedef unsigned short u16;
typedef unsigned int   u32;
typedef unsigned long long u64;

__device__ __forceinline__ u16 f2h(float f) {
  _Float16 h = (_Float16)f;                     // v_cvt_f16_f32, RNE
  return __builtin_bit_cast(u16, h);
}
// Fast gate math: v_exp + v_rcp. Robust at extremes.
__device__ __forceinline__ float sigm(float x) {
  return __builtin_amdgcn_rcpf(1.0f + __expf(-x));
}
__device__ __forceinline__ float tanh_fast(float x) {
  return 1.0f - 2.0f * __builtin_amdgcn_rcpf(__expf(2.0f * x) + 1.0f);
}

// ---------- K0: init h buf0 = 0, subflags/claims/ready = 0 ----------
__global__ __launch_bounds__(256) void k_init(u16* hbuf, u32* ctrs) {
  int t = blockIdx.x * 256 + threadIdx.x;       // 32768 threads
  ((u32*)hbuf)[t] = 0u;                         // zeroes buf0 (131072 B)
  ctrs[t] = 0u;                                 // all subflags + claim counters
  if (t == 0) ctrs[32768] = 0u;                 // ready counter
}

// ---------- K1: x (B,D,T) f32 -> xT[t][b][d] f16 ----------
__global__ __launch_bounds__(256) void k_xpose(const float* __restrict__ x,
                                               u16* __restrict__ xT) {
  __shared__ float lds[64][65];
  const int d0 = blockIdx.x * 64, t0 = blockIdx.y * 64, b = blockIdx.z;
  const int tid = threadIdx.x;
  const int tt = tid & 63, dr = tid >> 6;
  const float* xp = x + ((size_t)b * 512 + d0) * 512 + t0 + tt;
#pragma unroll
  for (int i = 0; i < 16; ++i) {
    int dd = i * 4 + dr;
    lds[dd][tt] = xp[(size_t)dd * 512];
  }
  __syncthreads();
  const int dp = tid & 31, rr = tid >> 5;
#pragma unroll
  for (int i = 0; i < 8; ++i) {
    int tt2 = i * 8 + rr;
    u32 lo = f2h(lds[dp * 2][tt2]);
    u32 hi = f2h(lds[dp * 2 + 1][tt2]);
    *(u32*)(xT + ((size_t)(t0 + tt2) * 64 + b) * 512 + d0 + dp * 2) = lo | (hi << 16);
  }
}

// ---------- K2: pack [W_ih | W_hh] rows into per-lane MFMA A-fragments (f16) ----------
// chunk c = (r*48 + ks)*4 + mt ; within-tile row m: gate=m&3, j=r*16+mt*4+(m>>2)
__global__ __launch_bounds__(256) void k_wfrag(const float* __restrict__ W_ih,
                                               const float* __restrict__ W_hh,
                                               u16* __restrict__ Wf) {
  int g = blockIdx.x * 256 + threadIdx.x;       // 786432 threads
  int lane = g & 63;
  int c  = g >> 6;                              // [0, 12288)
  int mt = c & 3;
  int cc = c >> 2;
  int ks = cc % 48;
  int r  = cc / 48;
  int m = lane & 15, q = lane >> 4;
  int gate = m & 3;
  int j = r * 16 + mt * 4 + (m >> 2);
  int row = gate * 1024 + j;
  const float* src = (ks < 16) ? (W_ih + (size_t)row * 512 + ks * 32 + q * 8)
                               : (W_hh + (size_t)row * 1024 + (ks - 16) * 32 + q * 8);
  union { u16 s[8]; uint4 v; } U;
#pragma unroll
  for (int i = 0; i < 8; ++i) U.s[i] = f2h(src[i]);
  *(uint4*)(Wf + ((size_t)c * 64 + lane) * 8) = U.v;
}

// ---------- K3: persistent cooperative recurrence ----------
// grid 256 = 4 groups x 64 blocks; block 512 = 8 waves.
// XCD CLAIM (r4, measured-good): thread 0 reads HW_REG_XCC_ID, claims a slot
// from per-XCD counters; g = xcd>>1, r = (xcd&1)|(slot<<1) — bijective, and
// localizes each group onto 2 XCDs (FETCH halved, confirmed by counters).
// SYNC (r4, measured-good): subflag per (g,r,mt) on its OWN 128B line.
// H-STORE (new): LDS-staged, sector-coalesced (see header comment).
__global__ __launch_bounds__(512, 2) void k_lstm(
    const u16* __restrict__ xT, const u16* __restrict__ Wf,
    u16* hbuf, u32* ctrs,
    const float* __restrict__ b_ih, const float* __restrict__ b_hh,
    const float* __restrict__ W_out, float* __restrict__ part) {
  __shared__ f32x4 red[2][8 * 4 * 64];    // [parity][wave][mt][lane], 64 KB
  __shared__ u16 hstage[16 * 24];         // h tile stage: 16 rows x 48B pitch
  __shared__ u32 scnt;                    // reducer-wave arrival counter
  __shared__ u32 sh_as;                   // claimed (xcd<<8)|slot
  const int tid = threadIdx.x;
  const int w = tid >> 6, lane = tid & 63;

  // --- claim (g, r) by physical XCD ---
  if (tid == 0) {
    u32 xcc;
    asm volatile("s_getreg_b32 %0, hwreg(HW_REG_XCC_ID)" : "=s"(xcc));
    xcc &= 7u;
    u32 sel = 0u, slot = 0u;
    for (int i = 0; i < 8; ++i) {
      u32 x = (xcc + (u32)i) & 7u;
      u32 s = __hip_atomic_fetch_add(ctrs + (x * 32 + 16), 1u,
                                     __ATOMIC_RELAXED, __HIP_MEMORY_SCOPE_AGENT);
      if (s < 32u) { sel = x; slot = s; break; }
    }
    sh_as = (sel << 8) | slot;
    scnt = 0u;
  }
  __syncthreads();
  const u32 as = sh_as;
  const int g = (int)((as >> 8) >> 1);
  const int r = (int)(((as >> 8) & 1u) | ((as & 255u) << 1));
  const int bg0 = g * 16, j0 = r * 16;
  const int n = lane & 15, q = lane >> 4;

  // Step-invariant weights -> registers (AGPR-eligible on gfx950)
  f16x8 wfr[6][4];
#pragma unroll
  for (int kl = 0; kl < 6; ++kl) {
    int ks = (kl < 2) ? (2 * w + kl) : (16 + 4 * w + (kl - 2));
#pragma unroll
    for (int mt = 0; mt < 4; ++mt) {
      size_t c = ((size_t)r * 48 + ks) * 4 + mt;
      wfr[kl][mt] = *(const f16x8*)(Wf + (c * 64 + lane) * 8);
    }
  }

  float bias0 = 0.f, bias1 = 0.f, bias2 = 0.f, bias3 = 0.f, wout = 0.f;
  if (w < 4) {
    int j = j0 + w * 4 + q;
    bias0 = b_ih[j]        + b_hh[j];
    bias1 = b_ih[1024 + j] + b_hh[1024 + j];
    bias2 = b_ih[2048 + j] + b_hh[2048 + j];
    bias3 = b_ih[3072 + j] + b_hh[3072 + j];
    wout  = W_out[j];
  }

  u32* ready = ctrs + 32768;
  // this block's subflag for reducer wave w (one per 128B line)
  u32* sf = ctrs + ((((u32)g * 64 + (u32)r) * 4 + (u32)w) << 5);
  // poll pointer: lane<32 -> producer block 8w+(lane>>2), mt=lane&3
  const u32* fp = ctrs + ((((u32)g * 64 + (8u * (u32)w + ((u32)lane >> 2))) * 4
                           + ((u32)lane & 3u)) << 5);

  // One-time grid barrier: all Wf loads done before part[] overwrites Wf
  __syncthreads();                        // each wave drains vmcnt -> wfr in regs
  if (tid == 0) {
    __hip_atomic_fetch_add(ready, 1u, __ATOMIC_RELAXED, __HIP_MEMORY_SCOPE_AGENT);
    while (__hip_atomic_load(ready, __ATOMIC_RELAXED, __HIP_MEMORY_SCOPE_AGENT) < 256u)
      __builtin_amdgcn_s_sleep(8);
  }
  __syncthreads();
  // zero own out-partial slice part[t=tid][g][r][0..16) (plain stores -> own L2)
  {
    f32x4 z = {0.f, 0.f, 0.f, 0.f};
    f32x4* p4 = (f32x4*)&part[((size_t)(tid * 4 + g) * 64 + r) * 16];
    p4[0] = z; p4[1] = z; p4[2] = z; p4[3] = z;
  }
  __syncthreads();                        // drain zero stores before any atomicAdd
  asm volatile("" ::: "memory");

  u16* hb0 = hbuf;
  u16* hb1 = hbuf + 64 * 1024;
  float c_state = 0.f;
  const f32x4 zero = {0.f, 0.f, 0.f, 0.f};

  for (int t = 0; t < 512; ++t) {
    const u16* hcur = (t & 1) ? hb1 : hb0;
    u16* hnext      = (t & 1) ? hb0 : hb1;
    const u16* xtb  = xT + (size_t)t * 32768;

    // flag-independent x loads first (ks = 2w, 2w+1)
    f16x8 bfr[6];
#pragma unroll
    for (int kl = 0; kl < 2; ++kl)
      bfr[kl] = *(const f16x8*)(xtb + (bg0 + n) * 512 + (2 * w + kl) * 32 + q * 8);

    // x-part MFMAs BEFORE the spin: overlap with flag wait (off the h chain)
    f32x4 acc[4];
#pragma unroll
    for (int mt = 0; mt < 4; ++mt)
      acc[mt] = __builtin_amdgcn_mfma_f32_16x16x32_f16(wfr[0][mt], bfr[0], zero, 0, 0, 0);
#pragma unroll
    for (int mt = 0; mt < 4; ++mt)
      acc[mt] = __builtin_amdgcn_mfma_f32_16x16x32_f16(wfr[1][mt], bfr[1], acc[mt], 0, 0, 0);
#pragma unroll
    for (int mt = 0; mt < 4; ++mt) asm volatile("" : "+v"(acc[mt]));

    // busy-poll own producer subflags (one padded line per lane, L2-cached)
    if (t > 0) {
      for (;;) {
        u32 f = 0xffffffffu;
        if (lane < 32)
          f = __hip_atomic_load(fp, __ATOMIC_RELAXED, __HIP_MEMORY_SCOPE_AGENT);
        if (__all((int)(f >= (u32)t))) break;
      }
    }
    asm volatile("" ::: "memory");   // no hoisting of h loads above the spin

    // h loads immediately after spin exit (ks-16 = 4w .. 4w+3)
#pragma unroll
    for (int kl = 2; kl < 6; ++kl) {
      const u64* p = (const u64*)(hcur + (bg0 + n) * 1024 + (4 * w + kl - 2) * 32 + q * 8);
      union { u64 u[2]; f16x8 v; } U;
      U.u[0] = __hip_atomic_load(p,     __ATOMIC_RELAXED, __HIP_MEMORY_SCOPE_AGENT);
      U.u[1] = __hip_atomic_load(p + 1, __ATOMIC_RELAXED, __HIP_MEMORY_SCOPE_AGENT);
      bfr[kl] = U.v;
    }

#pragma unroll
    for (int kl = 2; kl < 6; ++kl)
#pragma unroll
      for (int mt = 0; mt < 4; ++mt)
        acc[mt] = __builtin_amdgcn_mfma_f32_16x16x32_f16(wfr[kl][mt], bfr[kl], acc[mt], 0, 0, 0);

#pragma unroll
    for (int mt = 0; mt < 4; ++mt)
      red[t & 1][(w * 4 + mt) * 64 + lane] = acc[mt];
    __syncthreads();                      // the ONLY full-block barrier per step

    if (w < 4) {
      const int mt = w;
      // pairwise-tree reduce: depth 3 on the gate critical path
      const f32x4* rp = &red[t & 1][mt * 64 + lane];   // wv stride = 256 f32x4
      f32x4 s01 = rp[0]    + rp[256];
      f32x4 s23 = rp[512]  + rp[768];
      f32x4 s45 = rp[1024] + rp[1280];
      f32x4 s67 = rp[1536] + rp[1792];
      f32x4 s = (s01 + s23) + (s45 + s67);
      // lane owns all 4 gates of (b = bg0+n, j = j0+mt*4+q): regs = i,f,g,o
      float gi = s.x + bias0, gf = s.y + bias1, gg = s.z + bias2, go = s.w + bias3;
      c_state = sigm(gf) * c_state + sigm(gi) * tanh_fast(gg);
      float h = sigm(go) * tanh_fast(c_state);

      // --- stage h into LDS tile: hstage[row=n][col=mt*4+q], pitch 24 u16 ---
      hstage[n * 24 + mt * 4 + q] = (u32)__builtin_bit_cast(u16, (_Float16)h);
      asm volatile("s_waitcnt lgkmcnt(0)" ::: "memory");  // own ds_write done
      if (lane == 0)
        __hip_atomic_fetch_add(&scnt, 1u, __ATOMIC_RELAXED,
                               __HIP_MEMORY_SCOPE_WORKGROUP);
      // 4-wave sync among reducer waves (monotonic target; waves 4-7 skip)
      {
        const u32 tgt = 4u * ((u32)t + 1u);
        while (__hip_atomic_load(&scnt, __ATOMIC_RELAXED,
                                 __HIP_MEMORY_SCOPE_WORKGROUP) < tgt) {}
      }
      // --- sector-coalesced stores: wave mt stores rows 4mt..4mt+4 ---
      // 4 adjacent lanes x u64 = one contiguous 32B row per instruction.
      if (lane < 16) {
        int row = 4 * mt + (lane >> 2);
        int qt  = lane & 3;
        u64 v = *(const u64*)(hstage + row * 24 + qt * 4);   // ds_read_b64
        __hip_atomic_store((u64*)(hnext + (size_t)(bg0 + row) * 1024 + j0 + qt * 4),
                           v, __ATOMIC_RELAXED, __HIP_MEMORY_SCOPE_AGENT);
      }
      // drain own h stores, then release this wave's subflag ASAP
      asm volatile("s_waitcnt vmcnt(0)" ::: "memory");
      if (lane == 0)
        __hip_atomic_store(sf, (u32)(t + 1), __ATOMIC_RELAXED, __HIP_MEMORY_SCOPE_AGENT);
      // fused out-projection partial (fire-and-forget, own-L2 atomic)
      float p = h * wout;
      p += __shfl_xor(p, 16);
      p += __shfl_xor(p, 32);
      if (lane < 16)
        __hip_atomic_fetch_add(&part[((size_t)(t * 4 + g) * 64 + r) * 16 + lane], p,
                               __ATOMIC_RELAXED, __HIP_MEMORY_SCOPE_WORKGROUP);
    }
  }
}

// ---------- K4: out[b][t] = b_out + sum_r part[t][g][r][b&15] ----------
__global__ __launch_bounds__(256) void k_out(const float* __restrict__ part,
                                             const float* __restrict__ b_out,
                                             float* __restrict__ out) {
  int gi = blockIdx.x * 256 + threadIdx.x;      // 32768 threads
  int t = gi >> 6, b = gi & 63, g = b >> 4, b16 = b & 15;
  const float* p = part + ((size_t)(t * 4 + g) * 64) * 16 + b16;
  float s = b_out[0];
#pragma unroll 8
  for (int r = 0; r < 64; ++r) s += p[r * 16];
  out[(size_t)b * 512 + t] = s;
}

extern "C" void kernel_launch(void* const* d_in, const int* in_sizes, int n_in,
                              void* d_out, int out_size, void* d_ws, size_t ws_size,
                              hipStream_t stream) {
  const float* x    = (const float*)d_in[0];
  const float* W_ih = (const float*)d_in[1];
  const float* W_hh = (const float*)d_in[2];
  const float* b_ih = (const float*)d_in[3];
  const float* b_hh = (const float*)d_in[4];
  const float* Wout = (const float*)d_in[5];
  const float* bout = (const float*)d_in[6];
  float* out = (float*)d_out;

  unsigned char* ws = (unsigned char*)d_ws;
  u16* xT   = (u16*)(ws + WS_XT_OFF);
  u16* Wf   = (u16*)(ws + WS_WF_OFF);
  u16* hbuf = (u16*)(ws + WS_HB_OFF);
  u32* ctrs = (u32*)(ws + WS_CTR_OFF);
  float* part = (float*)(ws + WS_WF_OFF);       // reuses Wf region after load

  k_init<<<128, 256, 0, stream>>>(hbuf, ctrs);
  k_xpose<<<dim3(8, 8, 64), 256, 0, stream>>>(x, xT);
  k_wfrag<<<3072, 256, 0, stream>>>(W_ih, W_hh, Wf);

  void* args[8] = {&xT, &Wf, &hbuf, &ctrs, &b_ih, &b_hh, &Wout, &part};
  hipLaunchCooperativeKernel((const void*)k_lstm, dim3(256), dim3(512), args, 0, stream);

  k_out<<<128, 256, 0, stream>>>(part, bout, out);
}

// Round 6
// 1857.705 us; speedup vs baseline: 1.3143x; 1.3143x over previous
//
#include <hip/hip_runtime.h>
#include <cstddef>

// SimpleLSTM: B=64, D=512, T=512, H=1024, O=1 — fp16, XCD-claimed placement,
// SELF-VALIDATING TAGGED h-PACKETS (no flags, no drains: publish = 1 store,
// consume = validated load; the poll IS the data load).
// MODEL (r2-r5): time = 512 x serial coherence chain; bytes off the chain are
// free (r5: WRITE -196MB, time +/-0). Old chain: drain + flag + observe + load
// ≈ 4 LLC RTTs ≈ 10.7k cyc/step. New chain: ~1.5 RTTs.
// r3's failure modes fixed: (a) tags live in the SAME u64 as data (8B atomic,
// torn-proof); (b) each 64B line written by ONE wave's ONE coalesced store
// ([p][mt][b] layout) -> ONE invalidation/line/step (r3 had 8 -> refetch churn).
// Safety induction (parity double buffer, exact-match tags): block writes tag
// t+2 over tag t only after validating tag t+1 from ALL producers, which
// requires every group block passed barrier(t), i.e. finished reading tag t.
// ws layout (ends at 46,661,632 = r3-proven bound):
//   [0, 32MB)            xT: f16 [T=512][B=64][D=512]
//   [32MB, +12.58MB)     Wf: f16 A-frags [r=64][ks=48][mt=4][lane=64][8]
//                        (reused after weight load as out-partials
//                         part[t=512][g=4][r=64][b16=16] f32 = 8MB, atomicAdd'd)
//   [46,137,344, +512KB) pkt[parity=2][g=4][p=64][mt=4][b=16] x 16B packets
//                        packet = {h0,h1,h2,tagA | h3,tagB,pad,pad} (2 u64)
//                        claim/ready ctrs overlay first 1KB of parity-1 region
//                        (consumed before any parity-1 packet store).
#define WS_XT_OFF   0ull
#define WS_WF_OFF   33554432ull
#define WS_PK_OFF   46137344ull

typedef _Float16 f16x8 __attribute__((ext_vector_type(8)));
typedef float    f32x4 __attribute__((ext_vector_type(4)));
typedef unsigned short u16;
typedef unsigned int   u32;
typedef unsigned long long u64;

__device__ __forceinline__ u16 f2h(float f) {
  _Float16 h = (_Float16)f;                     // v_cvt_f16_f32, RNE
  return __builtin_bit_cast(u16, h);
}
// Fast gate math: v_exp + v_rcp. Robust at extremes.
__device__ __forceinline__ float sigm(float x) {
  return __builtin_amdgcn_rcpf(1.0f + __expf(-x));
}
__device__ __forceinline__ float tanh_fast(float x) {
  return 1.0f - 2.0f * __builtin_amdgcn_rcpf(__expf(2.0f * x) + 1.0f);
}

// ---------- K0: zero packet region (tags=0 == step-0 expectation, h=0) ----------
__global__ __launch_bounds__(256) void k_init(uint4* pkt16) {
  int t = blockIdx.x * 256 + threadIdx.x;       // 131072 threads x 16B = 512KB
  pkt16[t] = uint4{0u, 0u, 0u, 0u};
}

// ---------- K1: x (B,D,T) f32 -> xT[t][b][d] f16 ----------
__global__ __launch_bounds__(256) void k_xpose(const float* __restrict__ x,
                                               u16* __restrict__ xT) {
  __shared__ float lds[64][65];
  const int d0 = blockIdx.x * 64, t0 = blockIdx.y * 64, b = blockIdx.z;
  const int tid = threadIdx.x;
  const int tt = tid & 63, dr = tid >> 6;
  const float* xp = x + ((size_t)b * 512 + d0) * 512 + t0 + tt;
#pragma unroll
  for (int i = 0; i < 16; ++i) {
    int dd = i * 4 + dr;
    lds[dd][tt] = xp[(size_t)dd * 512];
  }
  __syncthreads();
  const int dp = tid & 31, rr = tid >> 5;
#pragma unroll
  for (int i = 0; i < 8; ++i) {
    int tt2 = i * 8 + rr;
    u32 lo = f2h(lds[dp * 2][tt2]);
    u32 hi = f2h(lds[dp * 2 + 1][tt2]);
    *(u32*)(xT + ((size_t)(t0 + tt2) * 64 + b) * 512 + d0 + dp * 2) = lo | (hi << 16);
  }
}

// ---------- K2: pack [W_ih | W_hh] rows into per-lane MFMA A-fragments (f16) ----------
// chunk c = (r*48 + ks)*4 + mt ; within-tile row m: gate=m&3, j=r*16+mt*4+(m>>2)
__global__ __launch_bounds__(256) void k_wfrag(const float* __restrict__ W_ih,
                                               const float* __restrict__ W_hh,
                                               u16* __restrict__ Wf) {
  int g = blockIdx.x * 256 + threadIdx.x;       // 786432 threads
  int lane = g & 63;
  int c  = g >> 6;                              // [0, 12288)
  int mt = c & 3;
  int cc = c >> 2;
  int ks = cc % 48;
  int r  = cc / 48;
  int m = lane & 15, q = lane >> 4;
  int gate = m & 3;
  int j = r * 16 + mt * 4 + (m >> 2);
  int row = gate * 1024 + j;
  const float* src = (ks < 16) ? (W_ih + (size_t)row * 512 + ks * 32 + q * 8)
                               : (W_hh + (size_t)row * 1024 + (ks - 16) * 32 + q * 8);
  union { u16 s[8]; uint4 v; } U;
#pragma unroll
  for (int i = 0; i < 8; ++i) U.s[i] = f2h(src[i]);
  *(uint4*)(Wf + ((size_t)c * 64 + lane) * 8) = U.v;
}

// ---------- K3: persistent cooperative recurrence ----------
// grid 256 = 4 groups x 64 blocks; block 512 = 8 waves; 1 block/CU.
// XCD CLAIM (r4, measured-good): g = xcd>>1, r = (xcd&1)|(slot<<1) — localizes
// each group onto 2 XCDs (FETCH halved, counter-confirmed).
// PACKETS: producer reducer-wave mt, after gates, gathers the 4 q-values per
// batch via 2 shfl_xor and fires per lane<16 TWO u64 agent stores forming
// packet {h0,h1,h2,tagA | h3,tagB,0,0} at pkt[(t+1)&1][g][r][mt][b=lane].
// The wave's 16 lanes cover 4 contiguous 64B lines -> 1-2 invalidations/line.
// CONSUMER wave w per kl' in [0,4): p = (4w+kl')*2+(q>>1), mt' = (q&1)*2 and
// mt'+1, b = n: retry-loads 4 u64, validates 4 embedded tags == t; frags
// assemble directly from validated words. Step-0: k_init zeros = tag 0, h=0.
__global__ __launch_bounds__(512, 2) void k_lstm(
    const u16* __restrict__ xT, const u16* __restrict__ Wf,
    u64* pkt,
    const float* __restrict__ b_ih, const float* __restrict__ b_hh,
    const float* __restrict__ W_out, float* __restrict__ part) {
  __shared__ f32x4 red[2][8 * 4 * 64];    // [parity][wave][mt][lane], 64 KB
  __shared__ u32 sh_as;                   // claimed (xcd<<8)|slot
  const int tid = threadIdx.x;
  const int w = tid >> 6, lane = tid & 63;

  // claim/ready overlay in parity-1 region (consumed before any pkt store;
  // ordering guaranteed by the ready barrier below)
  u32* cc = (u32*)(pkt + 32768);          // parity-1 base as u32

  // --- claim (g, r) by physical XCD ---
  if (tid == 0) {
    u32 xcc;
    asm volatile("s_getreg_b32 %0, hwreg(HW_REG_XCC_ID)" : "=s"(xcc));
    xcc &= 7u;
    u32 sel = 0u, slot = 0u;
    for (int i = 0; i < 8; ++i) {
      u32 x = (xcc + (u32)i) & 7u;
      u32 s = __hip_atomic_fetch_add(cc + x * 32, 1u,
                                     __ATOMIC_RELAXED, __HIP_MEMORY_SCOPE_AGENT);
      if (s < 32u) { sel = x; slot = s; break; }
    }
    sh_as = (sel << 8) | slot;
  }
  __syncthreads();
  const u32 as = sh_as;
  const int g = (int)((as >> 8) >> 1);
  const int r = (int)(((as >> 8) & 1u) | ((as & 255u) << 1));
  const int bg0 = g * 16, j0 = r * 16;
  const int n = lane & 15, q = lane >> 4;

  // Step-invariant weights -> registers
  f16x8 wfr[6][4];
#pragma unroll
  for (int kl = 0; kl < 6; ++kl) {
    int ks = (kl < 2) ? (2 * w + kl) : (16 + 4 * w + (kl - 2));
#pragma unroll
    for (int mt = 0; mt < 4; ++mt) {
      size_t c = ((size_t)r * 48 + ks) * 4 + mt;
      wfr[kl][mt] = *(const f16x8*)(Wf + (c * 64 + lane) * 8);
    }
  }

  float bias0 = 0.f, bias1 = 0.f, bias2 = 0.f, bias3 = 0.f, wout = 0.f;
  if (w < 4) {
    int j = j0 + w * 4 + q;
    bias0 = b_ih[j]        + b_hh[j];
    bias1 = b_ih[1024 + j] + b_hh[1024 + j];
    bias2 = b_ih[2048 + j] + b_hh[2048 + j];
    bias3 = b_ih[3072 + j] + b_hh[3072 + j];
    wout  = W_out[j];
  }

  // Consumer packet bases (u64 units within a parity): per kl',
  // idx = (((g*64 + p)*4 + mt')*16 + n)*2
  size_t cb[4];
#pragma unroll
  for (int kl = 0; kl < 4; ++kl) {
    int p = (4 * w + kl) * 2 + (q >> 1);
    cb[kl] = ((((size_t)g * 64 + p) * 4 + (size_t)((q & 1) * 2)) * 16 + n) * 2;
  }
  // Producer packet base (w<4, lane<16): block r, quarter mt=w, batch b=lane
  const size_t pwb = ((((size_t)g * 64 + r) * 4 + w) * 16 + (lane & 15)) * 2;

  // One-time grid barrier: all Wf loads done before part[] overwrites Wf.
  // Also orders: all claims (pre-increment) before any packet store (post-spin).
  __syncthreads();                        // drains vmcnt -> wfr in regs
  if (tid == 0) {
    __hip_atomic_fetch_add(cc + 256, 1u, __ATOMIC_RELAXED, __HIP_MEMORY_SCOPE_AGENT);
    while (__hip_atomic_load(cc + 256, __ATOMIC_RELAXED, __HIP_MEMORY_SCOPE_AGENT) < 256u)
      __builtin_amdgcn_s_sleep(8);
  }
  __syncthreads();
  // zero own out-partial slice part[t=tid][g][r][0..16)
  {
    f32x4 z = {0.f, 0.f, 0.f, 0.f};
    f32x4* p4 = (f32x4*)&part[((size_t)(tid * 4 + g) * 64 + r) * 16];
    p4[0] = z; p4[1] = z; p4[2] = z; p4[3] = z;
  }
  __syncthreads();                        // drain zero stores before any atomicAdd
  asm volatile("" ::: "memory");

  float c_state = 0.f;
  const f32x4 zero = {0.f, 0.f, 0.f, 0.f};

  for (int t = 0; t < 512; ++t) {
    const u16* xtb = xT + (size_t)t * 32768;

    // flag-independent x loads first (ks = 2w, 2w+1)
    f16x8 bfr[6];
#pragma unroll
    for (int kl = 0; kl < 2; ++kl)
      bfr[kl] = *(const f16x8*)(xtb + (bg0 + n) * 512 + (2 * w + kl) * 32 + q * 8);

    // x-part MFMAs BEFORE the packet wait: overlap with h propagation
    f32x4 acc[4];
#pragma unroll
    for (int mt = 0; mt < 4; ++mt)
      acc[mt] = __builtin_amdgcn_mfma_f32_16x16x32_f16(wfr[0][mt], bfr[0], zero, 0, 0, 0);
#pragma unroll
    for (int mt = 0; mt < 4; ++mt)
      acc[mt] = __builtin_amdgcn_mfma_f32_16x16x32_f16(wfr[1][mt], bfr[1], acc[mt], 0, 0, 0);
#pragma unroll
    for (int mt = 0; mt < 4; ++mt) asm volatile("" : "+v"(acc[mt]));

    // validated packet load: retry until ALL 16 embedded tags == t.
    // Between invalidations retries hit L2 (cheap); each line is invalidated
    // 1-2x/step (single-wave coalesced stores) so refetch churn is bounded.
    u64 a0[4], b0[4], a1[4], b1[4];
    {
      const u64* pb = pkt + (size_t)(t & 1) * 32768;
      const u32 et = (u32)t;
      for (;;) {
        bool ok = true;
#pragma unroll
        for (int kl = 0; kl < 4; ++kl) {
          const u64* p = pb + cb[kl];
          a0[kl] = __hip_atomic_load(p,      __ATOMIC_RELAXED, __HIP_MEMORY_SCOPE_AGENT);
          b0[kl] = __hip_atomic_load(p + 1,  __ATOMIC_RELAXED, __HIP_MEMORY_SCOPE_AGENT);
          a1[kl] = __hip_atomic_load(p + 32, __ATOMIC_RELAXED, __HIP_MEMORY_SCOPE_AGENT);
          b1[kl] = __hip_atomic_load(p + 33, __ATOMIC_RELAXED, __HIP_MEMORY_SCOPE_AGENT);
        }
#pragma unroll
        for (int kl = 0; kl < 4; ++kl) {
          ok = ok & ((u32)(a0[kl] >> 48) == et)
                  & (((u32)(b0[kl] >> 16) & 0xffffu) == et)
                  & ((u32)(a1[kl] >> 48) == et)
                  & (((u32)(b1[kl] >> 16) & 0xffffu) == et);
        }
        if (__all((int)ok)) break;
      }
    }
    asm volatile("" ::: "memory");

    // assemble h fragments from validated packets
#pragma unroll
    for (int kl = 0; kl < 4; ++kl) {
      union { u32 u[4]; f16x8 v; } Bu;
      Bu.u[0] = (u32)a0[kl];
      Bu.u[1] = ((u32)(a0[kl] >> 32) & 0xffffu) | (((u32)b0[kl] & 0xffffu) << 16);
      Bu.u[2] = (u32)a1[kl];
      Bu.u[3] = ((u32)(a1[kl] >> 32) & 0xffffu) | (((u32)b1[kl] & 0xffffu) << 16);
      bfr[kl + 2] = Bu.v;
    }

#pragma unroll
    for (int kl = 2; kl < 6; ++kl)
#pragma unroll
      for (int mt = 0; mt < 4; ++mt)
        acc[mt] = __builtin_amdgcn_mfma_f32_16x16x32_f16(wfr[kl][mt], bfr[kl], acc[mt], 0, 0, 0);

#pragma unroll
    for (int mt = 0; mt < 4; ++mt)
      red[t & 1][(w * 4 + mt) * 64 + lane] = acc[mt];
    __syncthreads();                      // the ONLY barrier per step

    if (w < 4) {
      const int mt = w;
      // pairwise-tree reduce: depth 3 on the gate critical path
      const f32x4* rp = &red[t & 1][mt * 64 + lane];   // wv stride = 256 f32x4
      f32x4 s01 = rp[0]    + rp[256];
      f32x4 s23 = rp[512]  + rp[768];
      f32x4 s45 = rp[1024] + rp[1280];
      f32x4 s67 = rp[1536] + rp[1792];
      f32x4 s = (s01 + s23) + (s45 + s67);
      // lane owns all 4 gates of (b = bg0+n, j = j0+mt*4+q): regs = i,f,g,o
      float gi = s.x + bias0, gf = s.y + bias1, gg = s.z + bias2, go = s.w + bias3;
      c_state = sigm(gf) * c_state + sigm(gi) * tanh_fast(gg);
      float h = sigm(go) * tanh_fast(c_state);

      // gather 4 q-values per batch to lanes<16 (2 shfl), fire tagged packet:
      // {h0,h1,h2,tagA | h3,tagB,0,0} — publish is these two stores, nothing else.
      u32 hv  = (u32)__builtin_bit_cast(u16, (_Float16)h);
      u32 o16 = (u32)__shfl_xor((int)hv, 16);
      u32 pair = (hv & 0xffffu) | (o16 << 16);       // at even q: {h_q, h_q+1}
      u32 o32 = (u32)__shfl_xor((int)pair, 32);      // at q==0: {h2, h3}
      if (lane < 16) {
        u64 tg = (u64)(u32)(t + 1);
        u64 Apkt = (u64)pair | ((u64)(o32 & 0xffffu) << 32) | (tg << 48);
        u64 Bpkt = (u64)((o32 >> 16) & 0xffffu) | (tg << 16);
        u64* pp = pkt + (size_t)((t + 1) & 1) * 32768 + pwb;
        __hip_atomic_store(pp,     Apkt, __ATOMIC_RELAXED, __HIP_MEMORY_SCOPE_AGENT);
        __hip_atomic_store(pp + 1, Bpkt, __ATOMIC_RELAXED, __HIP_MEMORY_SCOPE_AGENT);
      }
      // fused out-projection partial (fire-and-forget, own-L2 atomic)
      float p = h * wout;
      p += __shfl_xor(p, 16);
      p += __shfl_xor(p, 32);
      if (lane < 16)
        __hip_atomic_fetch_add(&part[((size_t)(t * 4 + g) * 64 + r) * 16 + lane], p,
                               __ATOMIC_RELAXED, __HIP_MEMORY_SCOPE_WORKGROUP);
    }
  }
}

// ---------- K4: out[b][t] = b_out + sum_r part[t][g][r][b&15] ----------
__global__ __launch_bounds__(256) void k_out(const float* __restrict__ part,
                                             const float* __restrict__ b_out,
                                             float* __restrict__ out) {
  int gi = blockIdx.x * 256 + threadIdx.x;      // 32768 threads
  int t = gi >> 6, b = gi & 63, g = b >> 4, b16 = b & 15;
  const float* p = part + ((size_t)(t * 4 + g) * 64) * 16 + b16;
  float s = b_out[0];
#pragma unroll 8
  for (int r = 0; r < 64; ++r) s += p[r * 16];
  out[(size_t)b * 512 + t] = s;
}

extern "C" void kernel_launch(void* const* d_in, const int* in_sizes, int n_in,
                              void* d_out, int out_size, void* d_ws, size_t ws_size,
                              hipStream_t stream) {
  const float* x    = (const float*)d_in[0];
  const float* W_ih = (const float*)d_in[1];
  const float* W_hh = (const float*)d_in[2];
  const float* b_ih = (const float*)d_in[3];
  const float* b_hh = (const float*)d_in[4];
  const float* Wout = (const float*)d_in[5];
  const float* bout = (const float*)d_in[6];
  float* out = (float*)d_out;

  unsigned char* ws = (unsigned char*)d_ws;
  u16* xT   = (u16*)(ws + WS_XT_OFF);
  u16* Wf   = (u16*)(ws + WS_WF_OFF);
  u64* pkt  = (u64*)(ws + WS_PK_OFF);
  float* part = (float*)(ws + WS_WF_OFF);       // reuses Wf region after load

  k_init<<<512, 256, 0, stream>>>((uint4*)pkt);
  k_xpose<<<dim3(8, 8, 64), 256, 0, stream>>>(x, xT);
  k_wfrag<<<3072, 256, 0, stream>>>(W_ih, W_hh, Wf);

  void* args[7] = {&xT, &Wf, &pkt, &b_ih, &b_hh, &Wout, &part};
  hipLaunchCooperativeKernel((const void*)k_lstm, dim3(256), dim3(512), args, 0, stream);

  k_out<<<128, 256, 0, stream>>>(part, bout, out);
}